// Round 11
// baseline (573.933 us; speedup 1.0000x reference)
//
#include <hip/hip_runtime.h>
#include <math.h>

#define N_NODES 100000
#define N_EDGES 3200000
#define EPS_F 1e-6f

#define NSLICE  8
#define SLICE_N 12500                     // 8 * 12500 = 100000, 50 KB LDS
#define NCHUNK  32
#define C_PAIRS (N_EDGES / 2 / NCHUNK)    // 50000 pairs (100K edges) per chunk

// ws layout (float indices) — 64 + 2E + E + E + NCHUNK*N + N = 16,100,064
// floats = 61.4 MiB (identical footprint to R7-R10 — already granted)
//   [1..4]   : sum(p0), sum(p1), sum(p0^2), sum(p1^2)
//   [5]      : sum(node_sum^2)
//   SD_OFF   : packed int2 (src,dst)[N_EDGES]     (25.6 MB)
//   VD_OFF   : v_src[e] then in-place cur[e]      (12.8 MB)
//   W_OFF    : w[e] = sigmoid(lg)/(imp+eps)       (12.8 MB)
//   PART_OFF : partials[NCHUNK][N_NODES]          (12.8 MB)
//   V_OFF    : packed v[N_NODES]                  (0.4 MB)
#define SD_OFF    64
#define VD_OFF    (SD_OFF + 2 * N_EDGES)
#define W_OFF     (VD_OFF + N_EDGES)
#define PART_OFF  (W_OFF + N_EDGES)
#define V_OFF     (PART_OFF + NCHUNK * N_NODES)
#define WS_FLOATS (V_OFF + N_NODES)

__device__ __forceinline__ float wave_reduce(float v) {
    #pragma unroll
    for (int off = 32; off > 0; off >>= 1) v += __shfl_down(v, off, 64);
    return v;
}

__device__ __forceinline__ void fadd_agent(float* p, float v) {
    unsafeAtomicAdd(p, v);
}

// ---------------- pass 0: pack v = nf[:,0] into a dense 400 KB table ----------------
__global__ __launch_bounds__(256) void packv_kernel(
    const float* __restrict__ nf, float* __restrict__ ws)
{
    const int i = blockIdx.x * blockDim.x + threadIdx.x;
    if (i < N_NODES) ws[V_OFF + i] = nf[i * 4];
}

// ---------------- pass 1: dtype-normalize edge_index -> int2 sd[] ----------------
// Pure vectorized transform: 2 edges per thread, int4 in / int4 out, no loop.
__global__ __launch_bounds__(256) void repack_kernel(
    const void* __restrict__ eidx, float* __restrict__ ws)
{
    const int* i32 = (const int*)eidx;

    // int64 values < 2^31 have zero hi-words at every odd int32 slot;
    // int32 has random node ids there (16 zeros ~ impossible).
    int any = 0;
    #pragma unroll
    for (int k = 1; k < 32; k += 2) any |= i32[k];
    const bool is32 = (any != 0);

    const int t = blockIdx.x * blockDim.x + threadIdx.x;   // pair index
    if (t >= N_EDGES / 2) return;

    int4 out;
    if (is32) {
        const int2 a = ((const int2*)i32)[t];                    // src pair
        const int2 b = ((const int2*)(i32 + N_EDGES))[t];        // dst pair
        out = make_int4(a.x, b.x, a.y, b.y);
    } else {
        const int4 a = ((const int4*)i32)[t];                    // src pair (2x i64)
        const int4 b = ((const int4*)(i32 + 2 * N_EDGES))[t];    // dst pair
        out = make_int4(a.x, b.x, a.z, b.z);
    }
    ((int4*)(ws + SD_OFF))[t] = out;
}

// ---------------- pass 2: variance sums + edge weight w[e] ----------------
// Exactly 1 pair per thread (6250 blocks x 256 = 1.6M pairs), zero loop:
// grid-stride loops with ~6 dynamic trips serialize at 1 latency/trip (R10).
__global__ __launch_bounds__(256) void varsum_kernel(
    const float2* __restrict__ params,
    const float*  __restrict__ logits,
    float*        __restrict__ ws)
{
    __shared__ float red[4][4];
    const int t = blockIdx.x * blockDim.x + threadIdx.x;   // pair index, exact

    const float4 pp = ((const float4*)params)[t];
    const float2 lg = ((const float2*)logits)[t];
    float2 w;
    w.x = (1.0f / (1.0f + __expf(-lg.x))) / (pp.x + pp.y + EPS_F);
    w.y = (1.0f / (1.0f + __expf(-lg.y))) / (pp.z + pp.w + EPS_F);
    ((float2*)(ws + W_OFF))[t] = w;

    float s0 = pp.x + pp.z;
    float s1 = pp.y + pp.w;
    float q0 = pp.x * pp.x + pp.z * pp.z;
    float q1 = pp.y * pp.y + pp.w * pp.w;

    s0 = wave_reduce(s0); s1 = wave_reduce(s1);
    q0 = wave_reduce(q0); q1 = wave_reduce(q1);

    const int wid = threadIdx.x >> 6;
    if ((threadIdx.x & 63) == 0) {
        red[wid][0] = s0; red[wid][1] = s1; red[wid][2] = q0; red[wid][3] = q1;
    }
    __syncthreads();
    if (threadIdx.x == 0) {
        float a0 = 0.f, a1 = 0.f, a2 = 0.f, a3 = 0.f;
        #pragma unroll
        for (int w2 = 0; w2 < 4; ++w2) {
            a0 += red[w2][0]; a1 += red[w2][1]; a2 += red[w2][2]; a3 += red[w2][3];
        }
        fadd_agent(ws + 1, a0); fadd_agent(ws + 2, a1);
        fadd_agent(ws + 3, a2); fadd_agent(ws + 4, a3);
    }
}

// Common scan geometry: 256 blocks (1/CU), 1024 thr, c = blockIdx&31 so all 8
// slice-blocks of chunk c land on one XCD (blockIdx%8 == c%8): the 8x sd
// re-scan is served by that XCD's L2. All scans use 4-pair ILP batching —
// un-batched scan loops serialize at ~1 L2 latency per iteration (R9: 263
// cy/iter measured).

// ---------------- pass 3: src-slice gather: vd[e] = v[src] ----------------
__global__ __launch_bounds__(1024) void vgatherS_kernel(float* __restrict__ ws)
{
    __shared__ float vs_lds[SLICE_N];   // 50 KB

    const int c  = blockIdx.x & (NCHUNK - 1);
    const int s  = blockIdx.x >> 5;
    const int lo = s * SLICE_N;

    const float* vtab = ws + V_OFF;
    for (int j = threadIdx.x; j < SLICE_N; j += 1024) vs_lds[j] = vtab[lo + j];
    __syncthreads();

    const int4* sdp = (const int4*)(ws + SD_OFF);
    float*      vd  = ws + VD_OFF;

    const int p0 = c * C_PAIRS;
    const int p1 = p0 + C_PAIRS;

    for (int base = p0 + threadIdx.x; base < p1; base += 4096) {
        int4 q4[4];
        #pragma unroll
        for (int k = 0; k < 4; ++k) {
            int p = base + k * 1024;
            p = (p < p1) ? p : (p1 - 1);   // clamp: loads stay unconditional
            q4[k] = sdp[p];
        }
        #pragma unroll
        for (int k = 0; k < 4; ++k) {
            const int p = base + k * 1024;
            if (p < p1) {
                const unsigned a = (unsigned)(q4[k].x - lo);
                const unsigned b = (unsigned)(q4[k].z - lo);
                if (a < SLICE_N) vd[2 * p]     = vs_lds[a];
                if (b < SLICE_N) vd[2 * p + 1] = vs_lds[b];
            }
        }
    }
}

// ---------------- pass 4: dst-slice: vd[e] <- |v_src - v_dst| * w[e] ----------------
__global__ __launch_bounds__(1024) void vgatherD_kernel(float* __restrict__ ws)
{
    __shared__ float vs_lds[SLICE_N];   // 50 KB

    const int c  = blockIdx.x & (NCHUNK - 1);
    const int s  = blockIdx.x >> 5;
    const int lo = s * SLICE_N;

    const float* vtab = ws + V_OFF;
    for (int j = threadIdx.x; j < SLICE_N; j += 1024) vs_lds[j] = vtab[lo + j];
    __syncthreads();

    const int4*   sdp = (const int4*)(ws + SD_OFF);
    float2*       vdp = (float2*)(ws + VD_OFF);
    const float2* wp  = (const float2*)(ws + W_OFF);

    const int p0 = c * C_PAIRS;
    const int p1 = p0 + C_PAIRS;

    for (int base = p0 + threadIdx.x; base < p1; base += 4096) {
        int4   q4[4];
        float2 vs4[4], w4[4];
        #pragma unroll
        for (int k = 0; k < 4; ++k) {
            int p = base + k * 1024;
            p = (p < p1) ? p : (p1 - 1);   // clamp: loads stay unconditional
            q4[k]  = sdp[p];
            vs4[k] = vdp[p];
            w4[k]  = wp[p];
        }
        #pragma unroll
        for (int k = 0; k < 4; ++k) {
            const int p = base + k * 1024;
            if (p < p1) {
                const unsigned a = (unsigned)(q4[k].y - lo);   // dst of edge 2p
                const unsigned b = (unsigned)(q4[k].w - lo);   // dst of edge 2p+1
                if ((a < SLICE_N) | (b < SLICE_N)) {
                    float2 outv = vs4[k];
                    if (a < SLICE_N) outv.x = fabsf(vs4[k].x - vs_lds[a]) * w4[k].x;
                    if (b < SLICE_N) outv.y = fabsf(vs4[k].y - vs_lds[b]) * w4[k].y;
                    if (a < SLICE_N && b < SLICE_N) vdp[p] = outv;
                    else if (a < SLICE_N) ((float*)vdp)[2 * p]     = outv.x;
                    else                  ((float*)vdp)[2 * p + 1] = outv.y;
                }
            }
        }
    }
}

// ---------------- pass 5: LDS-binned scatter of precomputed cur ----------------
__global__ __launch_bounds__(1024) void scatter_kernel(float* __restrict__ ws)
{
    __shared__ float bins[SLICE_N];   // 50 KB

    const int c  = blockIdx.x & (NCHUNK - 1);
    const int s  = blockIdx.x >> 5;
    const int lo = s * SLICE_N;

    for (int j = threadIdx.x; j < SLICE_N; j += 1024) bins[j] = 0.f;
    __syncthreads();

    const int4*   sdp = (const int4*)(ws + SD_OFF);
    const float2* cur = (const float2*)(ws + VD_OFF);

    const int p0 = c * C_PAIRS;
    const int p1 = p0 + C_PAIRS;

    for (int base = p0 + threadIdx.x; base < p1; base += 4096) {
        int4   q4[4];
        float2 u4[4];
        #pragma unroll
        for (int k = 0; k < 4; ++k) {
            int p = base + k * 1024;
            p = (p < p1) ? p : (p1 - 1);   // clamp: loads stay unconditional
            q4[k] = sdp[p];
            u4[k] = cur[p];
        }
        #pragma unroll
        for (int k = 0; k < 4; ++k) {
            const int p = base + k * 1024;
            if (p < p1) {
                const unsigned s0 = (unsigned)(q4[k].x - lo);
                const unsigned d0 = (unsigned)(q4[k].y - lo);
                const unsigned s1 = (unsigned)(q4[k].z - lo);
                const unsigned d1 = (unsigned)(q4[k].w - lo);
                if (d0 < SLICE_N) atomicAdd(&bins[d0],  u4[k].x);
                if (s0 < SLICE_N) atomicAdd(&bins[s0], -u4[k].x);
                if (d1 < SLICE_N) atomicAdd(&bins[d1],  u4[k].y);
                if (s1 < SLICE_N) atomicAdd(&bins[s1], -u4[k].y);
            }
        }
    }
    __syncthreads();

    float* pt = ws + PART_OFF + (size_t)c * N_NODES + lo;
    for (int j = threadIdx.x; j < SLICE_N; j += 1024) pt[j] = bins[j];
}

// ---------------- pass 6: merge partials, sum of squares ----------------
__global__ __launch_bounds__(256) void kcl_kernel(float* __restrict__ ws)
{
    const int i = blockIdx.x * blockDim.x + threadIdx.x;
    float acc = 0.f;
    if (i < N_NODES) {
        const float* p = ws + PART_OFF + i;
        float s = 0.f;
        #pragma unroll 8
        for (int c = 0; c < NCHUNK; ++c) s += p[(size_t)c * N_NODES];
        acc = s * s;
    }
    acc = wave_reduce(acc);
    if ((threadIdx.x & 63) == 0) fadd_agent(ws + 5, acc);
}

__global__ void final_kernel(const float* __restrict__ ws, float* __restrict__ out)
{
    const float s0 = ws[1], s1 = ws[2], q0 = ws[3], q1 = ws[4], k = ws[5];
    const float n  = (float)N_EDGES;
    const float var0 = (q0 - s0 * s0 / n) / (n - 1.0f);
    const float var1 = (q1 - s1 * s1 / n) / (n - 1.0f);
    out[0] = k / (float)N_NODES + 0.5f * (var0 + var1);
}

// ---------------- fallback (ws too small): agent-atomic scatter ----------------
#define FB_NODE_OFF 64
__global__ __launch_bounds__(256) void edge_kernel_fb(
    const float*  __restrict__ nf,
    const void*   __restrict__ eidx,
    const float*  __restrict__ logits,
    const float2* __restrict__ params,
    float*        __restrict__ ws)
{
    const int*       i32 = (const int*)eidx;
    const long long* i64 = (const long long*)eidx;
    int any = 0;
    #pragma unroll
    for (int k = 1; k < 32; k += 2) any |= i32[k];
    const bool is32 = (any != 0);

    float* node_sum = ws + FB_NODE_OFF;
    float* acc      = ws + 1;

    float s0 = 0.f, s1 = 0.f, q0 = 0.f, q1 = 0.f;
    const int tid    = blockIdx.x * blockDim.x + threadIdx.x;
    const int stride = gridDim.x * blockDim.x;
    for (int i = tid; i < N_EDGES; i += stride) {
        int src, dst;
        if (is32) { src = i32[i]; dst = i32[N_EDGES + i]; }
        else      { src = (int)i64[i]; dst = (int)i64[N_EDGES + i]; }
        const float2 ep = params[i];
        const float  p  = 1.0f / (1.0f + __expf(-logits[i]));
        const float cur = fabsf(nf[src * 4] - nf[dst * 4]) / (ep.x + ep.y + EPS_F) * p;
        fadd_agent(node_sum + dst,  cur);
        fadd_agent(node_sum + src, -cur);
        s0 += ep.x; s1 += ep.y; q0 += ep.x * ep.x; q1 += ep.y * ep.y;
    }
    s0 = wave_reduce(s0); s1 = wave_reduce(s1);
    q0 = wave_reduce(q0); q1 = wave_reduce(q1);
    if ((threadIdx.x & 63) == 0) {
        fadd_agent(acc + 0, s0); fadd_agent(acc + 1, s1);
        fadd_agent(acc + 2, q0); fadd_agent(acc + 3, q1);
    }
}

__global__ __launch_bounds__(256) void kcl_kernel_fb(float* __restrict__ ws)
{
    const float* node_sum = ws + FB_NODE_OFF;
    float acc = 0.f;
    const int tid    = blockIdx.x * blockDim.x + threadIdx.x;
    const int stride = gridDim.x * blockDim.x;
    for (int i = tid; i < N_NODES; i += stride) {
        const float v = node_sum[i];
        acc += v * v;
    }
    acc = wave_reduce(acc);
    if ((threadIdx.x & 63) == 0) fadd_agent(ws + 5, acc);
}

extern "C" void kernel_launch(void* const* d_in, const int* in_sizes, int n_in,
                              void* d_out, int out_size, void* d_ws, size_t ws_size,
                              hipStream_t stream) {
    const float*  nf     = (const float*)d_in[0];
    const void*   eidx   = d_in[1];
    const float*  logits = (const float*)d_in[2];
    const float2* params = (const float2*)d_in[3];
    float* ws  = (float*)d_ws;
    float* out = (float*)d_out;

    const size_t need = (size_t)WS_FLOATS * sizeof(float);   // 61.4 MiB (same as R7-R10)

    if (ws_size >= need) {
        hipMemsetAsync(d_ws, 0, 256, stream);
        packv_kernel<<<(N_NODES + 255) / 256, 256, 0, stream>>>(nf, ws);
        repack_kernel<<<(N_EDGES / 2 + 255) / 256, 256, 0, stream>>>(eidx, ws);
        varsum_kernel<<<N_EDGES / 2 / 256, 256, 0, stream>>>(params, logits, ws);
        vgatherS_kernel<<<NCHUNK * NSLICE, 1024, 0, stream>>>(ws);
        vgatherD_kernel<<<NCHUNK * NSLICE, 1024, 0, stream>>>(ws);
        scatter_kernel<<<NCHUNK * NSLICE, 1024, 0, stream>>>(ws);
        kcl_kernel<<<(N_NODES + 255) / 256, 256, 0, stream>>>(ws);
    } else {
        hipMemsetAsync(d_ws, 0, 256 + (size_t)N_NODES * sizeof(float), stream);
        edge_kernel_fb<<<2048, 256, 0, stream>>>(nf, eidx, logits, params, ws);
        kcl_kernel_fb<<<200, 256, 0, stream>>>(ws);
    }

    final_kernel<<<1, 1, 0, stream>>>(ws, out);
}

// Round 12
// 245.504 us; speedup vs baseline: 2.3378x; 2.3378x over previous
//
#include <hip/hip_runtime.h>
#include <math.h>

#define N_NODES 100000
#define N_EDGES 3200000
#define EPS_F 1e-6f

#define NSLICE  8
#define SLICE_N 12500                     // 8 * 12500 = 100000, 50 KB LDS
#define NCHUNK  32
#define C_PAIRS (N_EDGES / 2 / NCHUNK)    // 50000 pairs (100K edges) per chunk

#define NVARB   6250                      // varsum blocks (1 pair/thread, exact)
#define NKCLB   391                       // kcl blocks

// ws layout (float indices) — 61.5 MiB
//   SD_OFF   : packed int2 (src,dst)[N_EDGES]     (25.6 MB)
//   VD_OFF   : v_src[e] then in-place cur[e]      (12.8 MB)
//   W_OFF    : w[e] = sigmoid(lg)/(imp+eps)       (12.8 MB)
//   PART_OFF : partials[NCHUNK][N_NODES]          (12.8 MB)
//   V_OFF    : packed v[N_NODES]                  (0.4 MB)
//   VARP_OFF : per-block float4 {s0,s1,q0,q1}[NVARB]
//   KCLP_OFF : per-block kcl partial [NKCLB]
// NO same-address global atomics anywhere in the fast path (R11: 25K
// same-sector RMWs serialized at ~12ns each = 300us tail).
#define SD_OFF    64
#define VD_OFF    (SD_OFF + 2 * N_EDGES)
#define W_OFF     (VD_OFF + N_EDGES)
#define PART_OFF  (W_OFF + N_EDGES)
#define V_OFF     (PART_OFF + NCHUNK * N_NODES)
#define VARP_OFF  (V_OFF + N_NODES)
#define KCLP_OFF  (VARP_OFF + 4 * NVARB)
#define WS_FLOATS (KCLP_OFF + NKCLB + 64)

__device__ __forceinline__ float wave_reduce(float v) {
    #pragma unroll
    for (int off = 32; off > 0; off >>= 1) v += __shfl_down(v, off, 64);
    return v;
}

__device__ __forceinline__ void fadd_agent(float* p, float v) {
    unsafeAtomicAdd(p, v);   // fallback path only
}

// ---------------- pass 0: pack v = nf[:,0] into a dense 400 KB table ----------------
__global__ __launch_bounds__(256) void packv_kernel(
    const float* __restrict__ nf, float* __restrict__ ws)
{
    const int i = blockIdx.x * blockDim.x + threadIdx.x;
    if (i < N_NODES) ws[V_OFF + i] = nf[i * 4];
}

// ---------------- pass 1: dtype-normalize edge_index -> int2 sd[] ----------------
__global__ __launch_bounds__(256) void repack_kernel(
    const void* __restrict__ eidx, float* __restrict__ ws)
{
    const int* i32 = (const int*)eidx;

    // int64 values < 2^31 have zero hi-words at every odd int32 slot;
    // int32 has random node ids there (16 zeros ~ impossible).
    int any = 0;
    #pragma unroll
    for (int k = 1; k < 32; k += 2) any |= i32[k];
    const bool is32 = (any != 0);

    const int t = blockIdx.x * blockDim.x + threadIdx.x;   // pair index
    if (t >= N_EDGES / 2) return;

    int4 out;
    if (is32) {
        const int2 a = ((const int2*)i32)[t];                    // src pair
        const int2 b = ((const int2*)(i32 + N_EDGES))[t];        // dst pair
        out = make_int4(a.x, b.x, a.y, b.y);
    } else {
        const int4 a = ((const int4*)i32)[t];                    // src pair (2x i64)
        const int4 b = ((const int4*)(i32 + 2 * N_EDGES))[t];    // dst pair
        out = make_int4(a.x, b.x, a.z, b.z);
    }
    ((int4*)(ws + SD_OFF))[t] = out;
}

// ---------------- pass 2: variance sums + edge weight w[e] ----------------
// 1 pair/thread, zero loop; per-block partial store, ZERO global atomics.
__global__ __launch_bounds__(256) void varsum_kernel(
    const float2* __restrict__ params,
    const float*  __restrict__ logits,
    float*        __restrict__ ws)
{
    __shared__ float red[4][4];
    const int t = blockIdx.x * blockDim.x + threadIdx.x;   // pair index, exact

    const float4 pp = ((const float4*)params)[t];
    const float2 lg = ((const float2*)logits)[t];
    float2 w;
    w.x = (1.0f / (1.0f + __expf(-lg.x))) / (pp.x + pp.y + EPS_F);
    w.y = (1.0f / (1.0f + __expf(-lg.y))) / (pp.z + pp.w + EPS_F);
    ((float2*)(ws + W_OFF))[t] = w;

    float s0 = pp.x + pp.z;
    float s1 = pp.y + pp.w;
    float q0 = pp.x * pp.x + pp.z * pp.z;
    float q1 = pp.y * pp.y + pp.w * pp.w;

    s0 = wave_reduce(s0); s1 = wave_reduce(s1);
    q0 = wave_reduce(q0); q1 = wave_reduce(q1);

    const int wid = threadIdx.x >> 6;
    if ((threadIdx.x & 63) == 0) {
        red[wid][0] = s0; red[wid][1] = s1; red[wid][2] = q0; red[wid][3] = q1;
    }
    __syncthreads();
    if (threadIdx.x == 0) {
        float4 o;
        o.x = red[0][0] + red[1][0] + red[2][0] + red[3][0];
        o.y = red[0][1] + red[1][1] + red[2][1] + red[3][1];
        o.z = red[0][2] + red[1][2] + red[2][2] + red[3][2];
        o.w = red[0][3] + red[1][3] + red[2][3] + red[3][3];
        ((float4*)(ws + VARP_OFF))[blockIdx.x] = o;
    }
}

// Common scan geometry: 256 blocks (1/CU), 1024 thr, c = blockIdx&31 so all 8
// slice-blocks of chunk c land on one XCD: the 8x sd re-scan is L2-served.
// 4-pair ILP batching (un-batched scans serialize at ~1 L2 latency/iter).

// ---------------- pass 3: src-slice gather: vd[e] = v[src] ----------------
__global__ __launch_bounds__(1024) void vgatherS_kernel(float* __restrict__ ws)
{
    __shared__ float vs_lds[SLICE_N];   // 50 KB

    const int c  = blockIdx.x & (NCHUNK - 1);
    const int s  = blockIdx.x >> 5;
    const int lo = s * SLICE_N;

    const float* vtab = ws + V_OFF;
    for (int j = threadIdx.x; j < SLICE_N; j += 1024) vs_lds[j] = vtab[lo + j];
    __syncthreads();

    const int4* sdp = (const int4*)(ws + SD_OFF);
    float*      vd  = ws + VD_OFF;

    const int p0 = c * C_PAIRS;
    const int p1 = p0 + C_PAIRS;

    for (int base = p0 + threadIdx.x; base < p1; base += 4096) {
        int4 q4[4];
        #pragma unroll
        for (int k = 0; k < 4; ++k) {
            int p = base + k * 1024;
            p = (p < p1) ? p : (p1 - 1);   // clamp: loads stay unconditional
            q4[k] = sdp[p];
        }
        #pragma unroll
        for (int k = 0; k < 4; ++k) {
            const int p = base + k * 1024;
            if (p < p1) {
                const unsigned a = (unsigned)(q4[k].x - lo);
                const unsigned b = (unsigned)(q4[k].z - lo);
                if (a < SLICE_N) vd[2 * p]     = vs_lds[a];
                if (b < SLICE_N) vd[2 * p + 1] = vs_lds[b];
            }
        }
    }
}

// ---------------- pass 4: dst-slice: vd[e] <- |v_src - v_dst| * w[e] ----------------
__global__ __launch_bounds__(1024) void vgatherD_kernel(float* __restrict__ ws)
{
    __shared__ float vs_lds[SLICE_N];   // 50 KB

    const int c  = blockIdx.x & (NCHUNK - 1);
    const int s  = blockIdx.x >> 5;
    const int lo = s * SLICE_N;

    const float* vtab = ws + V_OFF;
    for (int j = threadIdx.x; j < SLICE_N; j += 1024) vs_lds[j] = vtab[lo + j];
    __syncthreads();

    const int4*   sdp = (const int4*)(ws + SD_OFF);
    float2*       vdp = (float2*)(ws + VD_OFF);
    const float2* wp  = (const float2*)(ws + W_OFF);

    const int p0 = c * C_PAIRS;
    const int p1 = p0 + C_PAIRS;

    for (int base = p0 + threadIdx.x; base < p1; base += 4096) {
        int4   q4[4];
        float2 vs4[4], w4[4];
        #pragma unroll
        for (int k = 0; k < 4; ++k) {
            int p = base + k * 1024;
            p = (p < p1) ? p : (p1 - 1);   // clamp: loads stay unconditional
            q4[k]  = sdp[p];
            vs4[k] = vdp[p];
            w4[k]  = wp[p];
        }
        #pragma unroll
        for (int k = 0; k < 4; ++k) {
            const int p = base + k * 1024;
            if (p < p1) {
                const unsigned a = (unsigned)(q4[k].y - lo);   // dst of edge 2p
                const unsigned b = (unsigned)(q4[k].w - lo);   // dst of edge 2p+1
                if ((a < SLICE_N) | (b < SLICE_N)) {
                    float2 outv = vs4[k];
                    if (a < SLICE_N) outv.x = fabsf(vs4[k].x - vs_lds[a]) * w4[k].x;
                    if (b < SLICE_N) outv.y = fabsf(vs4[k].y - vs_lds[b]) * w4[k].y;
                    if (a < SLICE_N && b < SLICE_N) vdp[p] = outv;
                    else if (a < SLICE_N) ((float*)vdp)[2 * p]     = outv.x;
                    else                  ((float*)vdp)[2 * p + 1] = outv.y;
                }
            }
        }
    }
}

// ---------------- pass 5: LDS-binned scatter of precomputed cur ----------------
__global__ __launch_bounds__(1024) void scatter_kernel(float* __restrict__ ws)
{
    __shared__ float bins[SLICE_N];   // 50 KB

    const int c  = blockIdx.x & (NCHUNK - 1);
    const int s  = blockIdx.x >> 5;
    const int lo = s * SLICE_N;

    for (int j = threadIdx.x; j < SLICE_N; j += 1024) bins[j] = 0.f;
    __syncthreads();

    const int4*   sdp = (const int4*)(ws + SD_OFF);
    const float2* cur = (const float2*)(ws + VD_OFF);

    const int p0 = c * C_PAIRS;
    const int p1 = p0 + C_PAIRS;

    for (int base = p0 + threadIdx.x; base < p1; base += 4096) {
        int4   q4[4];
        float2 u4[4];
        #pragma unroll
        for (int k = 0; k < 4; ++k) {
            int p = base + k * 1024;
            p = (p < p1) ? p : (p1 - 1);   // clamp: loads stay unconditional
            q4[k] = sdp[p];
            u4[k] = cur[p];
        }
        #pragma unroll
        for (int k = 0; k < 4; ++k) {
            const int p = base + k * 1024;
            if (p < p1) {
                const unsigned s0 = (unsigned)(q4[k].x - lo);
                const unsigned d0 = (unsigned)(q4[k].y - lo);
                const unsigned s1 = (unsigned)(q4[k].z - lo);
                const unsigned d1 = (unsigned)(q4[k].w - lo);
                if (d0 < SLICE_N) atomicAdd(&bins[d0],  u4[k].x);
                if (s0 < SLICE_N) atomicAdd(&bins[s0], -u4[k].x);
                if (d1 < SLICE_N) atomicAdd(&bins[d1],  u4[k].y);
                if (s1 < SLICE_N) atomicAdd(&bins[s1], -u4[k].y);
            }
        }
    }
    __syncthreads();

    float* pt = ws + PART_OFF + (size_t)c * N_NODES + lo;
    for (int j = threadIdx.x; j < SLICE_N; j += 1024) pt[j] = bins[j];
}

// ---------------- pass 6: merge partials, sum of squares (no atomics) ----------------
__global__ __launch_bounds__(256) void kcl_kernel(float* __restrict__ ws)
{
    __shared__ float red[4];
    const int i = blockIdx.x * blockDim.x + threadIdx.x;
    float acc = 0.f;
    if (i < N_NODES) {
        const float* p = ws + PART_OFF + i;
        float s = 0.f;
        #pragma unroll 8
        for (int c = 0; c < NCHUNK; ++c) s += p[(size_t)c * N_NODES];
        acc = s * s;
    }
    acc = wave_reduce(acc);
    if ((threadIdx.x & 63) == 0) red[threadIdx.x >> 6] = acc;
    __syncthreads();
    if (threadIdx.x == 0)
        ws[KCLP_OFF + blockIdx.x] = red[0] + red[1] + red[2] + red[3];
}

// ---------------- pass 7: final reduce of block partials ----------------
__global__ __launch_bounds__(1024) void final_kernel(
    const float* __restrict__ ws, float* __restrict__ out)
{
    __shared__ float red[16][5];
    float s0 = 0.f, s1 = 0.f, q0 = 0.f, q1 = 0.f, k = 0.f;

    const float4* vp = (const float4*)(ws + VARP_OFF);
    for (int i = threadIdx.x; i < NVARB; i += 1024) {
        const float4 v = vp[i];
        s0 += v.x; s1 += v.y; q0 += v.z; q1 += v.w;
    }
    for (int i = threadIdx.x; i < NKCLB; i += 1024) k += ws[KCLP_OFF + i];

    s0 = wave_reduce(s0); s1 = wave_reduce(s1);
    q0 = wave_reduce(q0); q1 = wave_reduce(q1);
    k  = wave_reduce(k);

    const int wid = threadIdx.x >> 6;
    if ((threadIdx.x & 63) == 0) {
        red[wid][0] = s0; red[wid][1] = s1; red[wid][2] = q0;
        red[wid][3] = q1; red[wid][4] = k;
    }
    __syncthreads();
    if (threadIdx.x == 0) {
        float a0 = 0.f, a1 = 0.f, a2 = 0.f, a3 = 0.f, a4 = 0.f;
        #pragma unroll
        for (int w = 0; w < 16; ++w) {
            a0 += red[w][0]; a1 += red[w][1]; a2 += red[w][2];
            a3 += red[w][3]; a4 += red[w][4];
        }
        const float n    = (float)N_EDGES;
        const float var0 = (a2 - a0 * a0 / n) / (n - 1.0f);
        const float var1 = (a3 - a1 * a1 / n) / (n - 1.0f);
        out[0] = a4 / (float)N_NODES + 0.5f * (var0 + var1);
    }
}

// ---------------- fallback (ws too small): agent-atomic scatter ----------------
#define FB_NODE_OFF 64
__global__ __launch_bounds__(256) void edge_kernel_fb(
    const float*  __restrict__ nf,
    const void*   __restrict__ eidx,
    const float*  __restrict__ logits,
    const float2* __restrict__ params,
    float*        __restrict__ ws)
{
    const int*       i32 = (const int*)eidx;
    const long long* i64 = (const long long*)eidx;
    int any = 0;
    #pragma unroll
    for (int k = 1; k < 32; k += 2) any |= i32[k];
    const bool is32 = (any != 0);

    float* node_sum = ws + FB_NODE_OFF;
    float* acc      = ws + 1;

    float s0 = 0.f, s1 = 0.f, q0 = 0.f, q1 = 0.f;
    const int tid    = blockIdx.x * blockDim.x + threadIdx.x;
    const int stride = gridDim.x * blockDim.x;
    for (int i = tid; i < N_EDGES; i += stride) {
        int src, dst;
        if (is32) { src = i32[i]; dst = i32[N_EDGES + i]; }
        else      { src = (int)i64[i]; dst = (int)i64[N_EDGES + i]; }
        const float2 ep = params[i];
        const float  p  = 1.0f / (1.0f + __expf(-logits[i]));
        const float cur = fabsf(nf[src * 4] - nf[dst * 4]) / (ep.x + ep.y + EPS_F) * p;
        fadd_agent(node_sum + dst,  cur);
        fadd_agent(node_sum + src, -cur);
        s0 += ep.x; s1 += ep.y; q0 += ep.x * ep.x; q1 += ep.y * ep.y;
    }
    s0 = wave_reduce(s0); s1 = wave_reduce(s1);
    q0 = wave_reduce(q0); q1 = wave_reduce(q1);
    if ((threadIdx.x & 63) == 0) {
        fadd_agent(acc + 0, s0); fadd_agent(acc + 1, s1);
        fadd_agent(acc + 2, q0); fadd_agent(acc + 3, q1);
    }
}

__global__ __launch_bounds__(256) void kcl_kernel_fb(float* __restrict__ ws)
{
    const float* node_sum = ws + FB_NODE_OFF;
    float acc = 0.f;
    const int tid    = blockIdx.x * blockDim.x + threadIdx.x;
    const int stride = gridDim.x * blockDim.x;
    for (int i = tid; i < N_NODES; i += stride) {
        const float v = node_sum[i];
        acc += v * v;
    }
    acc = wave_reduce(acc);
    if ((threadIdx.x & 63) == 0) fadd_agent(ws + 5, acc);
}

__global__ void final_kernel_fb(const float* __restrict__ ws, float* __restrict__ out)
{
    const float s0 = ws[1], s1 = ws[2], q0 = ws[3], q1 = ws[4], k = ws[5];
    const float n  = (float)N_EDGES;
    const float var0 = (q0 - s0 * s0 / n) / (n - 1.0f);
    const float var1 = (q1 - s1 * s1 / n) / (n - 1.0f);
    out[0] = k / (float)N_NODES + 0.5f * (var0 + var1);
}

extern "C" void kernel_launch(void* const* d_in, const int* in_sizes, int n_in,
                              void* d_out, int out_size, void* d_ws, size_t ws_size,
                              hipStream_t stream) {
    const float*  nf     = (const float*)d_in[0];
    const void*   eidx   = d_in[1];
    const float*  logits = (const float*)d_in[2];
    const float2* params = (const float2*)d_in[3];
    float* ws  = (float*)d_ws;
    float* out = (float*)d_out;

    const size_t need = (size_t)WS_FLOATS * sizeof(float);   // ~61.5 MiB

    if (ws_size >= need) {
        packv_kernel<<<(N_NODES + 255) / 256, 256, 0, stream>>>(nf, ws);
        repack_kernel<<<(N_EDGES / 2 + 255) / 256, 256, 0, stream>>>(eidx, ws);
        varsum_kernel<<<NVARB, 256, 0, stream>>>(params, logits, ws);
        vgatherS_kernel<<<NCHUNK * NSLICE, 1024, 0, stream>>>(ws);
        vgatherD_kernel<<<NCHUNK * NSLICE, 1024, 0, stream>>>(ws);
        scatter_kernel<<<NCHUNK * NSLICE, 1024, 0, stream>>>(ws);
        kcl_kernel<<<NKCLB, 256, 0, stream>>>(ws);
        final_kernel<<<1, 1024, 0, stream>>>(ws, out);
    } else {
        hipMemsetAsync(d_ws, 0, 256 + (size_t)N_NODES * sizeof(float), stream);
        edge_kernel_fb<<<2048, 256, 0, stream>>>(nf, eidx, logits, params, ws);
        kcl_kernel_fb<<<200, 256, 0, stream>>>(ws);
        final_kernel_fb<<<1, 1, 0, stream>>>(ws, out);
    }
}

// Round 13
// 200.059 us; speedup vs baseline: 2.8688x; 1.2272x over previous
//
#include <hip/hip_runtime.h>
#include <math.h>

#define N_NODES 100000
#define N_EDGES 3200000
#define EPS_F 1e-6f

#define NSLICE  8
#define SLICE_N 12500                     // 8 * 12500 = 100000, 50 KB LDS
#define NCHUNK  32
#define C_PAIRS (N_EDGES / 2 / NCHUNK)    // 50000 pairs (100K edges) per chunk

#define NVARB   6250                      // prep blocks (1 pair/thread, exact)
#define NKCLB   391                       // kcl blocks

// ws layout (4-byte words) — ~51.7 MB (well under evidenced 64.4 MB grant).
// Scan passes are L1-miss-BW bound (~7.7 TB/s aggregate measured R12), so
// streams are split per-consumer and payloads are bf16 to cut rescan bytes.
//   SRC_OFF  : int src[N_EDGES]                   (12.8 MB)
//   DST_OFF  : int dst[N_EDGES]                   (12.8 MB)
//   VD_OFF   : bf16 v_src[e], then in-place cur[e] (6.4 MB)
//   W_OFF    : bf16 w[e] = sigmoid(lg)/(imp+eps)   (6.4 MB)
//   PART_OFF : partials[NCHUNK][N_NODES]          (12.8 MB)
//   V_OFF    : packed fp32 v[N_NODES]              (0.4 MB)
//   VARP_OFF : per-block float4 {s0,s1,q0,q1}[NVARB]
//   KCLP_OFF : per-block kcl partial [NKCLB]
// NO same-address global atomics in the fast path (R11: ~12ns serial tail each).
#define SRC_OFF   64
#define DST_OFF   (SRC_OFF + N_EDGES)
#define VD_OFF    (DST_OFF + N_EDGES)
#define W_OFF     (VD_OFF + N_EDGES / 2)
#define PART_OFF  (W_OFF + N_EDGES / 2)
#define V_OFF     (PART_OFF + NCHUNK * N_NODES)
#define VARP_OFF  (V_OFF + N_NODES)
#define KCLP_OFF  (VARP_OFF + 4 * NVARB)
#define WS_FLOATS (KCLP_OFF + NKCLB + 64)

__device__ __forceinline__ float wave_reduce(float v) {
    #pragma unroll
    for (int off = 32; off > 0; off >>= 1) v += __shfl_down(v, off, 64);
    return v;
}

__device__ __forceinline__ void fadd_agent(float* p, float v) {
    unsafeAtomicAdd(p, v);   // fallback path only
}

// bf16 pack/unpack (RNE)
__device__ __forceinline__ unsigned short f2bf(float f) {
    unsigned u = __float_as_uint(f);
    unsigned r = ((u >> 16) & 1u) + 0x7FFFu;
    return (unsigned short)((u + r) >> 16);
}
__device__ __forceinline__ float bf2f(unsigned short h) {
    return __uint_as_float(((unsigned)h) << 16);
}

// ---------------- pass 1: prep = packv + repack(split) + varsum + w ----------------
// 1 pair/thread, zero loop, per-block partial store, zero global atomics.
__global__ __launch_bounds__(256) void prep_kernel(
    const float*  __restrict__ nf,
    const void*   __restrict__ eidx,
    const float*  __restrict__ logits,
    const float2* __restrict__ params,
    float*        __restrict__ ws)
{
    __shared__ float red[4][4];
    const int* i32 = (const int*)eidx;

    // int64 values < 2^31 have zero hi-words at every odd int32 slot;
    // int32 has random node ids there (16 zeros ~ impossible).
    int any = 0;
    #pragma unroll
    for (int k = 1; k < 32; k += 2) any |= i32[k];
    const bool is32 = (any != 0);

    const int t = blockIdx.x * blockDim.x + threadIdx.x;   // pair index, exact

    // indices -> split SRC / DST streams
    int2 sp, dp;
    if (is32) {
        sp = ((const int2*)i32)[t];
        dp = ((const int2*)(i32 + N_EDGES))[t];
    } else {
        const int4 a = ((const int4*)i32)[t];                  // 2x int64 src
        const int4 b = ((const int4*)(i32 + 2 * N_EDGES))[t];  // 2x int64 dst
        sp = make_int2(a.x, a.z);
        dp = make_int2(b.x, b.z);
    }
    ((int2*)(ws + SRC_OFF))[t] = sp;
    ((int2*)(ws + DST_OFF))[t] = dp;

    // w + variance sums
    const float4 pp = ((const float4*)params)[t];
    const float2 lg = ((const float2*)logits)[t];
    const float w0 = (1.0f / (1.0f + __expf(-lg.x))) / (pp.x + pp.y + EPS_F);
    const float w1 = (1.0f / (1.0f + __expf(-lg.y))) / (pp.z + pp.w + EPS_F);
    ((unsigned*)(ws + W_OFF))[t] = (unsigned)f2bf(w0) | ((unsigned)f2bf(w1) << 16);

    // packed v table (first 100K threads)
    if (t < N_NODES) ws[V_OFF + t] = nf[t * 4];

    float s0 = pp.x + pp.z;
    float s1 = pp.y + pp.w;
    float q0 = pp.x * pp.x + pp.z * pp.z;
    float q1 = pp.y * pp.y + pp.w * pp.w;

    s0 = wave_reduce(s0); s1 = wave_reduce(s1);
    q0 = wave_reduce(q0); q1 = wave_reduce(q1);

    const int wid = threadIdx.x >> 6;
    if ((threadIdx.x & 63) == 0) {
        red[wid][0] = s0; red[wid][1] = s1; red[wid][2] = q0; red[wid][3] = q1;
    }
    __syncthreads();
    if (threadIdx.x == 0) {
        float4 o;
        o.x = red[0][0] + red[1][0] + red[2][0] + red[3][0];
        o.y = red[0][1] + red[1][1] + red[2][1] + red[3][1];
        o.z = red[0][2] + red[1][2] + red[2][2] + red[3][2];
        o.w = red[0][3] + red[1][3] + red[2][3] + red[3][3];
        ((float4*)(ws + VARP_OFF))[blockIdx.x] = o;
    }
}

// Scan geometry: 256 blocks (1/CU), 1024 thr, c = blockIdx&31 so all 8
// slice-blocks of chunk c land on one XCD (blockIdx%8 == c%8): rescans are
// L2-served. 4-pair ILP batching throughout (un-batched scans serialize at
// ~1 L2 latency/iter — R9).

// ---------------- pass 2: src-slice gather: vd[e] = bf16(v[src]) ----------------
__global__ __launch_bounds__(1024) void vgatherS_kernel(float* __restrict__ ws)
{
    __shared__ float vs_lds[SLICE_N];   // 50 KB

    const int c  = blockIdx.x & (NCHUNK - 1);
    const int s  = blockIdx.x >> 5;
    const int lo = s * SLICE_N;

    const float* vtab = ws + V_OFF;
    for (int j = threadIdx.x; j < SLICE_N; j += 1024) vs_lds[j] = vtab[lo + j];
    __syncthreads();

    const int2*     srcp = (const int2*)(ws + SRC_OFF);
    unsigned short* vd   = (unsigned short*)(ws + VD_OFF);

    const int p0 = c * C_PAIRS;
    const int p1 = p0 + C_PAIRS;

    for (int base = p0 + threadIdx.x; base < p1; base += 4096) {
        int2 q4[4];
        #pragma unroll
        for (int k = 0; k < 4; ++k) {
            int p = base + k * 1024;
            p = (p < p1) ? p : (p1 - 1);   // clamp: loads stay unconditional
            q4[k] = srcp[p];
        }
        #pragma unroll
        for (int k = 0; k < 4; ++k) {
            const int p = base + k * 1024;
            if (p < p1) {
                const unsigned a = (unsigned)(q4[k].x - lo);
                const unsigned b = (unsigned)(q4[k].y - lo);
                if (a < SLICE_N) vd[2 * p]     = f2bf(vs_lds[a]);
                if (b < SLICE_N) vd[2 * p + 1] = f2bf(vs_lds[b]);
            }
        }
    }
}

// ---------------- pass 3: dst-slice: vd[e] <- bf16(|v_src - v_dst| * w[e]) ----------------
// In-place: each edge's dst is in exactly one slice -> exactly-once rewrite.
// Unconditional pair loads may race with other blocks' stores, but those
// lanes' values are discarded (masks are disjoint across slice blocks).
__global__ __launch_bounds__(1024) void vgatherD_kernel(float* __restrict__ ws)
{
    __shared__ float vs_lds[SLICE_N];   // 50 KB

    const int c  = blockIdx.x & (NCHUNK - 1);
    const int s  = blockIdx.x >> 5;
    const int lo = s * SLICE_N;

    const float* vtab = ws + V_OFF;
    for (int j = threadIdx.x; j < SLICE_N; j += 1024) vs_lds[j] = vtab[lo + j];
    __syncthreads();

    const int2*     dstp = (const int2*)(ws + DST_OFF);
    const unsigned* vdw  = (const unsigned*)(ws + VD_OFF);
    const unsigned* ww   = (const unsigned*)(ws + W_OFF);
    unsigned short* vd   = (unsigned short*)(ws + VD_OFF);

    const int p0 = c * C_PAIRS;
    const int p1 = p0 + C_PAIRS;

    for (int base = p0 + threadIdx.x; base < p1; base += 4096) {
        int2     q4[4];
        unsigned v4[4], w4[4];
        #pragma unroll
        for (int k = 0; k < 4; ++k) {
            int p = base + k * 1024;
            p = (p < p1) ? p : (p1 - 1);   // clamp: loads stay unconditional
            q4[k] = dstp[p];
            v4[k] = vdw[p];
            w4[k] = ww[p];
        }
        #pragma unroll
        for (int k = 0; k < 4; ++k) {
            const int p = base + k * 1024;
            if (p < p1) {
                const unsigned a = (unsigned)(q4[k].x - lo);
                const unsigned b = (unsigned)(q4[k].y - lo);
                if (a < SLICE_N) {
                    const float cur = fabsf(bf2f((unsigned short)(v4[k] & 0xFFFF)) - vs_lds[a])
                                      * bf2f((unsigned short)(w4[k] & 0xFFFF));
                    vd[2 * p] = f2bf(cur);
                }
                if (b < SLICE_N) {
                    const float cur = fabsf(bf2f((unsigned short)(v4[k] >> 16)) - vs_lds[b])
                                      * bf2f((unsigned short)(w4[k] >> 16));
                    vd[2 * p + 1] = f2bf(cur);
                }
            }
        }
    }
}

// ---------------- pass 4: LDS-binned scatter of precomputed cur ----------------
__global__ __launch_bounds__(1024) void scatter_kernel(float* __restrict__ ws)
{
    __shared__ float bins[SLICE_N];   // 50 KB

    const int c  = blockIdx.x & (NCHUNK - 1);
    const int s  = blockIdx.x >> 5;
    const int lo = s * SLICE_N;

    for (int j = threadIdx.x; j < SLICE_N; j += 1024) bins[j] = 0.f;
    __syncthreads();

    const int2*     srcp = (const int2*)(ws + SRC_OFF);
    const int2*     dstp = (const int2*)(ws + DST_OFF);
    const unsigned* curw = (const unsigned*)(ws + VD_OFF);

    const int p0 = c * C_PAIRS;
    const int p1 = p0 + C_PAIRS;

    for (int base = p0 + threadIdx.x; base < p1; base += 4096) {
        int2     s4[4], d4[4];
        unsigned u4[4];
        #pragma unroll
        for (int k = 0; k < 4; ++k) {
            int p = base + k * 1024;
            p = (p < p1) ? p : (p1 - 1);   // clamp: loads stay unconditional
            s4[k] = srcp[p];
            d4[k] = dstp[p];
            u4[k] = curw[p];
        }
        #pragma unroll
        for (int k = 0; k < 4; ++k) {
            const int p = base + k * 1024;
            if (p < p1) {
                const float c0 = bf2f((unsigned short)(u4[k] & 0xFFFF));
                const float c1 = bf2f((unsigned short)(u4[k] >> 16));
                const unsigned s0 = (unsigned)(s4[k].x - lo);
                const unsigned d0 = (unsigned)(d4[k].x - lo);
                const unsigned s1 = (unsigned)(s4[k].y - lo);
                const unsigned d1 = (unsigned)(d4[k].y - lo);
                if (d0 < SLICE_N) atomicAdd(&bins[d0],  c0);
                if (s0 < SLICE_N) atomicAdd(&bins[s0], -c0);
                if (d1 < SLICE_N) atomicAdd(&bins[d1],  c1);
                if (s1 < SLICE_N) atomicAdd(&bins[s1], -c1);
            }
        }
    }
    __syncthreads();

    float* pt = ws + PART_OFF + (size_t)c * N_NODES + lo;
    for (int j = threadIdx.x; j < SLICE_N; j += 1024) pt[j] = bins[j];
}

// ---------------- pass 5: merge partials, sum of squares (no atomics) ----------------
__global__ __launch_bounds__(256) void kcl_kernel(float* __restrict__ ws)
{
    __shared__ float red[4];
    const int i = blockIdx.x * blockDim.x + threadIdx.x;
    float acc = 0.f;
    if (i < N_NODES) {
        const float* p = ws + PART_OFF + i;
        float s = 0.f;
        #pragma unroll 8
        for (int c = 0; c < NCHUNK; ++c) s += p[(size_t)c * N_NODES];
        acc = s * s;
    }
    acc = wave_reduce(acc);
    if ((threadIdx.x & 63) == 0) red[threadIdx.x >> 6] = acc;
    __syncthreads();
    if (threadIdx.x == 0)
        ws[KCLP_OFF + blockIdx.x] = red[0] + red[1] + red[2] + red[3];
}

// ---------------- pass 6: final reduce of block partials ----------------
__global__ __launch_bounds__(1024) void final_kernel(
    const float* __restrict__ ws, float* __restrict__ out)
{
    __shared__ float red[16][5];
    float s0 = 0.f, s1 = 0.f, q0 = 0.f, q1 = 0.f, k = 0.f;

    const float4* vp = (const float4*)(ws + VARP_OFF);
    for (int i = threadIdx.x; i < NVARB; i += 1024) {
        const float4 v = vp[i];
        s0 += v.x; s1 += v.y; q0 += v.z; q1 += v.w;
    }
    for (int i = threadIdx.x; i < NKCLB; i += 1024) k += ws[KCLP_OFF + i];

    s0 = wave_reduce(s0); s1 = wave_reduce(s1);
    q0 = wave_reduce(q0); q1 = wave_reduce(q1);
    k  = wave_reduce(k);

    const int wid = threadIdx.x >> 6;
    if ((threadIdx.x & 63) == 0) {
        red[wid][0] = s0; red[wid][1] = s1; red[wid][2] = q0;
        red[wid][3] = q1; red[wid][4] = k;
    }
    __syncthreads();
    if (threadIdx.x == 0) {
        float a0 = 0.f, a1 = 0.f, a2 = 0.f, a3 = 0.f, a4 = 0.f;
        #pragma unroll
        for (int w = 0; w < 16; ++w) {
            a0 += red[w][0]; a1 += red[w][1]; a2 += red[w][2];
            a3 += red[w][3]; a4 += red[w][4];
        }
        const float n    = (float)N_EDGES;
        const float var0 = (a2 - a0 * a0 / n) / (n - 1.0f);
        const float var1 = (a3 - a1 * a1 / n) / (n - 1.0f);
        out[0] = a4 / (float)N_NODES + 0.5f * (var0 + var1);
    }
}

// ---------------- fallback (ws too small): agent-atomic scatter ----------------
#define FB_NODE_OFF 64
__global__ __launch_bounds__(256) void edge_kernel_fb(
    const float*  __restrict__ nf,
    const void*   __restrict__ eidx,
    const float*  __restrict__ logits,
    const float2* __restrict__ params,
    float*        __restrict__ ws)
{
    const int*       i32 = (const int*)eidx;
    const long long* i64 = (const long long*)eidx;
    int any = 0;
    #pragma unroll
    for (int k = 1; k < 32; k += 2) any |= i32[k];
    const bool is32 = (any != 0);

    float* node_sum = ws + FB_NODE_OFF;
    float* acc      = ws + 1;

    float s0 = 0.f, s1 = 0.f, q0 = 0.f, q1 = 0.f;
    const int tid    = blockIdx.x * blockDim.x + threadIdx.x;
    const int stride = gridDim.x * blockDim.x;
    for (int i = tid; i < N_EDGES; i += stride) {
        int src, dst;
        if (is32) { src = i32[i]; dst = i32[N_EDGES + i]; }
        else      { src = (int)i64[i]; dst = (int)i64[N_EDGES + i]; }
        const float2 ep = params[i];
        const float  p  = 1.0f / (1.0f + __expf(-logits[i]));
        const float cur = fabsf(nf[src * 4] - nf[dst * 4]) / (ep.x + ep.y + EPS_F) * p;
        fadd_agent(node_sum + dst,  cur);
        fadd_agent(node_sum + src, -cur);
        s0 += ep.x; s1 += ep.y; q0 += ep.x * ep.x; q1 += ep.y * ep.y;
    }
    s0 = wave_reduce(s0); s1 = wave_reduce(s1);
    q0 = wave_reduce(q0); q1 = wave_reduce(q1);
    if ((threadIdx.x & 63) == 0) {
        fadd_agent(acc + 0, s0); fadd_agent(acc + 1, s1);
        fadd_agent(acc + 2, q0); fadd_agent(acc + 3, q1);
    }
}

__global__ __launch_bounds__(256) void kcl_kernel_fb(float* __restrict__ ws)
{
    const float* node_sum = ws + FB_NODE_OFF;
    float acc = 0.f;
    const int tid    = blockIdx.x * blockDim.x + threadIdx.x;
    const int stride = gridDim.x * blockDim.x;
    for (int i = tid; i < N_NODES; i += stride) {
        const float v = node_sum[i];
        acc += v * v;
    }
    acc = wave_reduce(acc);
    if ((threadIdx.x & 63) == 0) fadd_agent(ws + 5, acc);
}

__global__ void final_kernel_fb(const float* __restrict__ ws, float* __restrict__ out)
{
    const float s0 = ws[1], s1 = ws[2], q0 = ws[3], q1 = ws[4], k = ws[5];
    const float n  = (float)N_EDGES;
    const float var0 = (q0 - s0 * s0 / n) / (n - 1.0f);
    const float var1 = (q1 - s1 * s1 / n) / (n - 1.0f);
    out[0] = k / (float)N_NODES + 0.5f * (var0 + var1);
}

extern "C" void kernel_launch(void* const* d_in, const int* in_sizes, int n_in,
                              void* d_out, int out_size, void* d_ws, size_t ws_size,
                              hipStream_t stream) {
    const float*  nf     = (const float*)d_in[0];
    const void*   eidx   = d_in[1];
    const float*  logits = (const float*)d_in[2];
    const float2* params = (const float2*)d_in[3];
    float* ws  = (float*)d_ws;
    float* out = (float*)d_out;

    const size_t need = (size_t)WS_FLOATS * sizeof(float);   // ~51.7 MB

    if (ws_size >= need) {
        prep_kernel<<<NVARB, 256, 0, stream>>>(nf, eidx, logits, params, ws);
        vgatherS_kernel<<<NCHUNK * NSLICE, 1024, 0, stream>>>(ws);
        vgatherD_kernel<<<NCHUNK * NSLICE, 1024, 0, stream>>>(ws);
        scatter_kernel<<<NCHUNK * NSLICE, 1024, 0, stream>>>(ws);
        kcl_kernel<<<NKCLB, 256, 0, stream>>>(ws);
        final_kernel<<<1, 1024, 0, stream>>>(ws, out);
    } else {
        hipMemsetAsync(d_ws, 0, 256 + (size_t)N_NODES * sizeof(float), stream);
        edge_kernel_fb<<<2048, 256, 0, stream>>>(nf, eidx, logits, params, ws);
        kcl_kernel_fb<<<200, 256, 0, stream>>>(ws);
        final_kernel_fb<<<1, 1, 0, stream>>>(ws, out);
    }
}

// Round 14
// 182.781 us; speedup vs baseline: 3.1400x; 1.0945x over previous
//
#include <hip/hip_runtime.h>
#include <math.h>

#define N_NODES 100000
#define N_EDGES 3200000
#define EPS_F 1e-6f

// gather slicing: bf16 v-table in LDS -> 25000 nodes / 50KB, only 4 slices
#define GSLICE_N 25000
#define GNSLICE  4
#define GNCHUNK  64
#define GC_PAIRS (N_EDGES / 2 / GNCHUNK)  // 25000 pairs per chunk

// scatter slicing: fp32 bins must stay 12500/50KB -> 8 slices
#define SLICE_N 12500
#define NSLICE  8
#define NCHUNK  32
#define C_PAIRS (N_EDGES / 2 / NCHUNK)    // 50000 pairs per chunk

#define NVARB   6250                      // prep blocks (1 pair/thread, exact)
#define NKCLB   391                       // kcl blocks

// ws layout (4-byte words) — ~51.7 MB
//   SRC_OFF  : int src[N_EDGES]                    (12.8 MB)
//   DST_OFF  : int dst[N_EDGES]                    (12.8 MB)
//   VD_OFF   : bf16 v_src[e], then in-place cur[e]  (6.4 MB)
//   W_OFF    : bf16 w[e] = sigmoid(lg)/(imp+eps)    (6.4 MB)
//   PART_OFF : partials[NCHUNK][N_NODES]           (12.8 MB)
//   V_OFF    : packed fp32 v[N_NODES]               (0.4 MB)
//   VARP_OFF : per-block float4 {s0,s1,q0,q1}[NVARB]
//   KCLP_OFF : per-block kcl partial [NKCLB]
// NO same-address global atomics in the fast path (R11: ~12ns serial tail each).
#define SRC_OFF   64
#define DST_OFF   (SRC_OFF + N_EDGES)
#define VD_OFF    (DST_OFF + N_EDGES)
#define W_OFF     (VD_OFF + N_EDGES / 2)
#define PART_OFF  (W_OFF + N_EDGES / 2)
#define V_OFF     (PART_OFF + NCHUNK * N_NODES)
#define VARP_OFF  (V_OFF + N_NODES)
#define KCLP_OFF  (VARP_OFF + 4 * NVARB)
#define WS_FLOATS (KCLP_OFF + NKCLB + 64)

__device__ __forceinline__ float wave_reduce(float v) {
    #pragma unroll
    for (int off = 32; off > 0; off >>= 1) v += __shfl_down(v, off, 64);
    return v;
}

__device__ __forceinline__ void fadd_agent(float* p, float v) {
    unsafeAtomicAdd(p, v);   // fallback path only
}

// bf16 pack/unpack (RNE)
__device__ __forceinline__ unsigned short f2bf(float f) {
    unsigned u = __float_as_uint(f);
    unsigned r = ((u >> 16) & 1u) + 0x7FFFu;
    return (unsigned short)((u + r) >> 16);
}
__device__ __forceinline__ float bf2f(unsigned short h) {
    return __uint_as_float(((unsigned)h) << 16);
}

// ---------------- pass 1: prep = packv + repack(split) + varsum + w ----------------
__global__ __launch_bounds__(256) void prep_kernel(
    const float*  __restrict__ nf,
    const void*   __restrict__ eidx,
    const float*  __restrict__ logits,
    const float2* __restrict__ params,
    float*        __restrict__ ws)
{
    __shared__ float red[4][4];
    const int* i32 = (const int*)eidx;

    // int64 values < 2^31 have zero hi-words at every odd int32 slot;
    // int32 has random node ids there (16 zeros ~ impossible).
    int any = 0;
    #pragma unroll
    for (int k = 1; k < 32; k += 2) any |= i32[k];
    const bool is32 = (any != 0);

    const int t = blockIdx.x * blockDim.x + threadIdx.x;   // pair index, exact

    int2 sp, dp;
    if (is32) {
        sp = ((const int2*)i32)[t];
        dp = ((const int2*)(i32 + N_EDGES))[t];
    } else {
        const int4 a = ((const int4*)i32)[t];                  // 2x int64 src
        const int4 b = ((const int4*)(i32 + 2 * N_EDGES))[t];  // 2x int64 dst
        sp = make_int2(a.x, a.z);
        dp = make_int2(b.x, b.z);
    }
    ((int2*)(ws + SRC_OFF))[t] = sp;
    ((int2*)(ws + DST_OFF))[t] = dp;

    const float4 pp = ((const float4*)params)[t];
    const float2 lg = ((const float2*)logits)[t];
    const float w0 = (1.0f / (1.0f + __expf(-lg.x))) / (pp.x + pp.y + EPS_F);
    const float w1 = (1.0f / (1.0f + __expf(-lg.y))) / (pp.z + pp.w + EPS_F);
    ((unsigned*)(ws + W_OFF))[t] = (unsigned)f2bf(w0) | ((unsigned)f2bf(w1) << 16);

    if (t < N_NODES) ws[V_OFF + t] = nf[t * 4];

    float s0 = pp.x + pp.z;
    float s1 = pp.y + pp.w;
    float q0 = pp.x * pp.x + pp.z * pp.z;
    float q1 = pp.y * pp.y + pp.w * pp.w;

    s0 = wave_reduce(s0); s1 = wave_reduce(s1);
    q0 = wave_reduce(q0); q1 = wave_reduce(q1);

    const int wid = threadIdx.x >> 6;
    if ((threadIdx.x & 63) == 0) {
        red[wid][0] = s0; red[wid][1] = s1; red[wid][2] = q0; red[wid][3] = q1;
    }
    __syncthreads();
    if (threadIdx.x == 0) {
        float4 o;
        o.x = red[0][0] + red[1][0] + red[2][0] + red[3][0];
        o.y = red[0][1] + red[1][1] + red[2][1] + red[3][1];
        o.z = red[0][2] + red[1][2] + red[2][2] + red[3][2];
        o.w = red[0][3] + red[1][3] + red[2][3] + red[3][3];
        ((float4*)(ws + VARP_OFF))[blockIdx.x] = o;
    }
}

// Gather geometry: 256 blocks (4 slices x 64 chunks), 1024 thr. c=blockIdx&63
// -> the 4 slice-blocks of chunk c share blockIdx%8 (one XCD): rescans L2-hit.
// bf16 LDS v-table halves the rescan factor vs fp32 (R13: 8 slices).

// ---------------- pass 2: src-slice gather: vd[e] = bf16(v[src]) ----------------
__global__ __launch_bounds__(1024) void vgatherS_kernel(float* __restrict__ ws)
{
    __shared__ unsigned short vs_lds[GSLICE_N];   // 50 KB bf16

    const int c  = blockIdx.x & (GNCHUNK - 1);
    const int s  = blockIdx.x >> 6;
    const int lo = s * GSLICE_N;

    const float* vtab = ws + V_OFF;
    for (int j = threadIdx.x; j < GSLICE_N; j += 1024) vs_lds[j] = f2bf(vtab[lo + j]);
    __syncthreads();

    const int2*     srcp = (const int2*)(ws + SRC_OFF);
    unsigned short* vd   = (unsigned short*)(ws + VD_OFF);

    const int p0 = c * GC_PAIRS;
    const int p1 = p0 + GC_PAIRS;

    for (int base = p0 + threadIdx.x; base < p1; base += 4096) {
        int2 q4[4];
        #pragma unroll
        for (int k = 0; k < 4; ++k) {
            int p = base + k * 1024;
            p = (p < p1) ? p : (p1 - 1);   // clamp: loads stay unconditional
            q4[k] = srcp[p];
        }
        #pragma unroll
        for (int k = 0; k < 4; ++k) {
            const int p = base + k * 1024;
            if (p < p1) {
                const unsigned a = (unsigned)(q4[k].x - lo);
                const unsigned b = (unsigned)(q4[k].y - lo);
                if (a < GSLICE_N) vd[2 * p]     = vs_lds[a];
                if (b < GSLICE_N) vd[2 * p + 1] = vs_lds[b];
            }
        }
    }
}

// ---------------- pass 3: dst-slice: vd[e] <- bf16(|v_src - v_dst| * w[e]) ----------------
__global__ __launch_bounds__(1024) void vgatherD_kernel(float* __restrict__ ws)
{
    __shared__ unsigned short vs_lds[GSLICE_N];   // 50 KB bf16

    const int c  = blockIdx.x & (GNCHUNK - 1);
    const int s  = blockIdx.x >> 6;
    const int lo = s * GSLICE_N;

    const float* vtab = ws + V_OFF;
    for (int j = threadIdx.x; j < GSLICE_N; j += 1024) vs_lds[j] = f2bf(vtab[lo + j]);
    __syncthreads();

    const int2*     dstp = (const int2*)(ws + DST_OFF);
    const unsigned* vdw  = (const unsigned*)(ws + VD_OFF);
    const unsigned* ww   = (const unsigned*)(ws + W_OFF);
    unsigned short* vd   = (unsigned short*)(ws + VD_OFF);

    const int p0 = c * GC_PAIRS;
    const int p1 = p0 + GC_PAIRS;

    for (int base = p0 + threadIdx.x; base < p1; base += 4096) {
        int2     q4[4];
        unsigned v4[4], w4[4];
        #pragma unroll
        for (int k = 0; k < 4; ++k) {
            int p = base + k * 1024;
            p = (p < p1) ? p : (p1 - 1);   // clamp: loads stay unconditional
            q4[k] = dstp[p];
            v4[k] = vdw[p];
            w4[k] = ww[p];
        }
        #pragma unroll
        for (int k = 0; k < 4; ++k) {
            const int p = base + k * 1024;
            if (p < p1) {
                const unsigned a = (unsigned)(q4[k].x - lo);
                const unsigned b = (unsigned)(q4[k].y - lo);
                if (a < GSLICE_N) {
                    const float cur = fabsf(bf2f((unsigned short)(v4[k] & 0xFFFF)) - bf2f(vs_lds[a]))
                                      * bf2f((unsigned short)(w4[k] & 0xFFFF));
                    vd[2 * p] = f2bf(cur);
                }
                if (b < GSLICE_N) {
                    const float cur = fabsf(bf2f((unsigned short)(v4[k] >> 16)) - bf2f(vs_lds[b]))
                                      * bf2f((unsigned short)(w4[k] >> 16));
                    vd[2 * p + 1] = f2bf(cur);
                }
            }
        }
    }
}

// ---------------- pass 4: LDS-binned scatter, 8-pair ILP batch ----------------
// fp32 bins (accumulation) keep this at 8 slices of 12500. 762 GB/s/XCD
// observed (R13) says latency not L2 BW binds it -> deeper load batching.
__global__ __launch_bounds__(1024) void scatter_kernel(float* __restrict__ ws)
{
    __shared__ float bins[SLICE_N];   // 50 KB

    const int c  = blockIdx.x & (NCHUNK - 1);
    const int s  = blockIdx.x >> 5;
    const int lo = s * SLICE_N;

    for (int j = threadIdx.x; j < SLICE_N; j += 1024) bins[j] = 0.f;
    __syncthreads();

    const int2*     srcp = (const int2*)(ws + SRC_OFF);
    const int2*     dstp = (const int2*)(ws + DST_OFF);
    const unsigned* curw = (const unsigned*)(ws + VD_OFF);

    const int p0 = c * C_PAIRS;
    const int p1 = p0 + C_PAIRS;

    for (int base = p0 + threadIdx.x; base < p1; base += 8192) {
        int2     s8[8], d8[8];
        unsigned u8[8];
        #pragma unroll
        for (int k = 0; k < 8; ++k) {
            int p = base + k * 1024;
            p = (p < p1) ? p : (p1 - 1);   // clamp: loads stay unconditional
            s8[k] = srcp[p];
            d8[k] = dstp[p];
            u8[k] = curw[p];
        }
        #pragma unroll
        for (int k = 0; k < 8; ++k) {
            const int p = base + k * 1024;
            if (p < p1) {
                const float c0 = bf2f((unsigned short)(u8[k] & 0xFFFF));
                const float c1 = bf2f((unsigned short)(u8[k] >> 16));
                const unsigned s0 = (unsigned)(s8[k].x - lo);
                const unsigned d0 = (unsigned)(d8[k].x - lo);
                const unsigned s1 = (unsigned)(s8[k].y - lo);
                const unsigned d1 = (unsigned)(d8[k].y - lo);
                if (d0 < SLICE_N) atomicAdd(&bins[d0],  c0);
                if (s0 < SLICE_N) atomicAdd(&bins[s0], -c0);
                if (d1 < SLICE_N) atomicAdd(&bins[d1],  c1);
                if (s1 < SLICE_N) atomicAdd(&bins[s1], -c1);
            }
        }
    }
    __syncthreads();

    float* pt = ws + PART_OFF + (size_t)c * N_NODES + lo;
    for (int j = threadIdx.x; j < SLICE_N; j += 1024) pt[j] = bins[j];
}

// ---------------- pass 5: merge partials, sum of squares (no atomics) ----------------
__global__ __launch_bounds__(256) void kcl_kernel(float* __restrict__ ws)
{
    __shared__ float red[4];
    const int i = blockIdx.x * blockDim.x + threadIdx.x;
    float acc = 0.f;
    if (i < N_NODES) {
        const float* p = ws + PART_OFF + i;
        float s = 0.f;
        #pragma unroll 8
        for (int c = 0; c < NCHUNK; ++c) s += p[(size_t)c * N_NODES];
        acc = s * s;
    }
    acc = wave_reduce(acc);
    if ((threadIdx.x & 63) == 0) red[threadIdx.x >> 6] = acc;
    __syncthreads();
    if (threadIdx.x == 0)
        ws[KCLP_OFF + blockIdx.x] = red[0] + red[1] + red[2] + red[3];
}

// ---------------- pass 6: final reduce of block partials ----------------
__global__ __launch_bounds__(1024) void final_kernel(
    const float* __restrict__ ws, float* __restrict__ out)
{
    __shared__ float red[16][5];
    float s0 = 0.f, s1 = 0.f, q0 = 0.f, q1 = 0.f, k = 0.f;

    const float4* vp = (const float4*)(ws + VARP_OFF);
    for (int i = threadIdx.x; i < NVARB; i += 1024) {
        const float4 v = vp[i];
        s0 += v.x; s1 += v.y; q0 += v.z; q1 += v.w;
    }
    for (int i = threadIdx.x; i < NKCLB; i += 1024) k += ws[KCLP_OFF + i];

    s0 = wave_reduce(s0); s1 = wave_reduce(s1);
    q0 = wave_reduce(q0); q1 = wave_reduce(q1);
    k  = wave_reduce(k);

    const int wid = threadIdx.x >> 6;
    if ((threadIdx.x & 63) == 0) {
        red[wid][0] = s0; red[wid][1] = s1; red[wid][2] = q0;
        red[wid][3] = q1; red[wid][4] = k;
    }
    __syncthreads();
    if (threadIdx.x == 0) {
        float a0 = 0.f, a1 = 0.f, a2 = 0.f, a3 = 0.f, a4 = 0.f;
        #pragma unroll
        for (int w = 0; w < 16; ++w) {
            a0 += red[w][0]; a1 += red[w][1]; a2 += red[w][2];
            a3 += red[w][3]; a4 += red[w][4];
        }
        const float n    = (float)N_EDGES;
        const float var0 = (a2 - a0 * a0 / n) / (n - 1.0f);
        const float var1 = (a3 - a1 * a1 / n) / (n - 1.0f);
        out[0] = a4 / (float)N_NODES + 0.5f * (var0 + var1);
    }
}

// ---------------- fallback (ws too small): agent-atomic scatter ----------------
#define FB_NODE_OFF 64
__global__ __launch_bounds__(256) void edge_kernel_fb(
    const float*  __restrict__ nf,
    const void*   __restrict__ eidx,
    const float*  __restrict__ logits,
    const float2* __restrict__ params,
    float*        __restrict__ ws)
{
    const int*       i32 = (const int*)eidx;
    const long long* i64 = (const long long*)eidx;
    int any = 0;
    #pragma unroll
    for (int k = 1; k < 32; k += 2) any |= i32[k];
    const bool is32 = (any != 0);

    float* node_sum = ws + FB_NODE_OFF;
    float* acc      = ws + 1;

    float s0 = 0.f, s1 = 0.f, q0 = 0.f, q1 = 0.f;
    const int tid    = blockIdx.x * blockDim.x + threadIdx.x;
    const int stride = gridDim.x * blockDim.x;
    for (int i = tid; i < N_EDGES; i += stride) {
        int src, dst;
        if (is32) { src = i32[i]; dst = i32[N_EDGES + i]; }
        else      { src = (int)i64[i]; dst = (int)i64[N_EDGES + i]; }
        const float2 ep = params[i];
        const float  p  = 1.0f / (1.0f + __expf(-logits[i]));
        const float cur = fabsf(nf[src * 4] - nf[dst * 4]) / (ep.x + ep.y + EPS_F) * p;
        fadd_agent(node_sum + dst,  cur);
        fadd_agent(node_sum + src, -cur);
        s0 += ep.x; s1 += ep.y; q0 += ep.x * ep.x; q1 += ep.y * ep.y;
    }
    s0 = wave_reduce(s0); s1 = wave_reduce(s1);
    q0 = wave_reduce(q0); q1 = wave_reduce(q1);
    if ((threadIdx.x & 63) == 0) {
        fadd_agent(acc + 0, s0); fadd_agent(acc + 1, s1);
        fadd_agent(acc + 2, q0); fadd_agent(acc + 3, q1);
    }
}

__global__ __launch_bounds__(256) void kcl_kernel_fb(float* __restrict__ ws)
{
    const float* node_sum = ws + FB_NODE_OFF;
    float acc = 0.f;
    const int tid    = blockIdx.x * blockDim.x + threadIdx.x;
    const int stride = gridDim.x * blockDim.x;
    for (int i = tid; i < N_NODES; i += stride) {
        const float v = node_sum[i];
        acc += v * v;
    }
    acc = wave_reduce(acc);
    if ((threadIdx.x & 63) == 0) fadd_agent(ws + 5, acc);
}

__global__ void final_kernel_fb(const float* __restrict__ ws, float* __restrict__ out)
{
    const float s0 = ws[1], s1 = ws[2], q0 = ws[3], q1 = ws[4], k = ws[5];
    const float n  = (float)N_EDGES;
    const float var0 = (q0 - s0 * s0 / n) / (n - 1.0f);
    const float var1 = (q1 - s1 * s1 / n) / (n - 1.0f);
    out[0] = k / (float)N_NODES + 0.5f * (var0 + var1);
}

extern "C" void kernel_launch(void* const* d_in, const int* in_sizes, int n_in,
                              void* d_out, int out_size, void* d_ws, size_t ws_size,
                              hipStream_t stream) {
    const float*  nf     = (const float*)d_in[0];
    const void*   eidx   = d_in[1];
    const float*  logits = (const float*)d_in[2];
    const float2* params = (const float2*)d_in[3];
    float* ws  = (float*)d_ws;
    float* out = (float*)d_out;

    const size_t need = (size_t)WS_FLOATS * sizeof(float);   // ~51.7 MB

    if (ws_size >= need) {
        prep_kernel<<<NVARB, 256, 0, stream>>>(nf, eidx, logits, params, ws);
        vgatherS_kernel<<<GNCHUNK * GNSLICE, 1024, 0, stream>>>(ws);
        vgatherD_kernel<<<GNCHUNK * GNSLICE, 1024, 0, stream>>>(ws);
        scatter_kernel<<<NCHUNK * NSLICE, 1024, 0, stream>>>(ws);
        kcl_kernel<<<NKCLB, 256, 0, stream>>>(ws);
        final_kernel<<<1, 1024, 0, stream>>>(ws, out);
    } else {
        hipMemsetAsync(d_ws, 0, 256 + (size_t)N_NODES * sizeof(float), stream);
        edge_kernel_fb<<<2048, 256, 0, stream>>>(nf, eidx, logits, params, ws);
        kcl_kernel_fb<<<200, 256, 0, stream>>>(ws);
        final_kernel_fb<<<1, 1, 0, stream>>>(ws, out);
    }
}